// Round 10
// baseline (444.165 us; speedup 1.0000x reference)
//
#include <hip/hip_runtime.h>
#include <cstdint>
#include <cstddef>

// ---------------------------------------------------------------------------
// SparseConv3DBlock: BN(inference)+SiLU -> gather(27 neighbors) -> implicit GEMM
// N=200000, F_IN=64, F_OUT=128, K=27.  bf16 MFMA path.
//   k1: y_bf16[N][64] = silu(bn(x))
//   k2: Wt_bf16[27][128][64] = transpose(W)
//   k3: BM=128, 8 waves, r5 skeleton, but MFMA = 32x32x16 (32 FLOP per LDS
//       A-byte vs 16 for 16x16x32): wave (rg4 x cg2) = 32 rows x 64 cols,
//       per phase 4 A-ds_reads + 8 MFMA -> block LDS reads 128->32 while
//       matrix work is unchanged. Depth-1 reg staging, one sync/phase.
//   r6/r8 lesson: natural VGPR (~116) must stay under cap (128).
// ---------------------------------------------------------------------------

typedef __attribute__((ext_vector_type(8))) short short8;
typedef __attribute__((ext_vector_type(16))) float f32x16;

#define N_VOX 200000
#define F_IN 64
#define F_OUT 128
#define KOFF 27
#define BM 128

__device__ __forceinline__ short f2bf(float f) {
  unsigned u = __builtin_bit_cast(unsigned, f);
  u += 0x7fffu + ((u >> 16) & 1u);   // RNE
  return (short)(u >> 16);
}

// ---------------- Kernel 1: BN + SiLU + cast to bf16 ----------------------
__global__ __launch_bounds__(256) void bn_silu_kernel(
    const float* __restrict__ x, const float* __restrict__ gamma,
    const float* __restrict__ beta, const float* __restrict__ mean,
    const float* __restrict__ var, short* __restrict__ y) {
  __shared__ float s_scale[F_IN], s_bias[F_IN];
  int tid = threadIdx.x;
  if (tid < F_IN) {
    float s = gamma[tid] * rsqrtf(var[tid] + 1e-5f);
    s_scale[tid] = s;
    s_bias[tid] = beta[tid] - mean[tid] * s;
  }
  __syncthreads();
  size_t i = ((size_t)blockIdx.x * 256 + tid) * 8;   // 12.8M total, exact
  int f0 = (int)(i & (F_IN - 1));                    // multiple of 8
  float4 x0 = *(const float4*)(x + i);
  float4 x1 = *(const float4*)(x + i + 4);
  float v[8] = {x0.x, x0.y, x0.z, x0.w, x1.x, x1.y, x1.z, x1.w};
  short8 o;
#pragma unroll
  for (int j = 0; j < 8; ++j) {
    float t = v[j] * s_scale[f0 + j] + s_bias[f0 + j];
    float sg = 1.0f / (1.0f + __expf(-t));
    o[j] = f2bf(t * sg);
  }
  *(short8*)(y + i) = o;
}

// ---------------- Kernel 2: W[27][64][128] f32 -> Wt[27][128][64] bf16 ----
__global__ __launch_bounds__(256) void wprep_kernel(
    const float* __restrict__ W, short* __restrict__ Wt) {
  int tid = blockIdx.x * 256 + threadIdx.x;        // 27*128*8 = 27648 threads
  if (tid >= KOFF * F_OUT * 8) return;
  int k = tid >> 10;                               // /(128*8)
  int r = tid & 1023;
  int o = r >> 3;
  int f0 = (r & 7) * 8;
  short8 vv;
#pragma unroll
  for (int i = 0; i < 8; ++i)
    vv[i] = f2bf(W[((size_t)k * F_IN + f0 + i) * F_OUT + o]);
  *(short8*)(Wt + ((size_t)k * F_OUT + o) * F_IN + f0) = vv;
}

// ---------------- Kernel 3: 32x32x16 reg-staged gather + implicit GEMM ----
// BM=128 voxels/block, 512 threads = 8 waves. Wave (rg=w>>1, cg=w&1):
// rows rg*32..+32, cols cg*64..+64 (2 col-tiles of 32). Per phase per wave:
// 4 ksteps x (1 A ds_read_b128 + 2 MFMA 32x32x16). B reg-double-buffered.
// Phase k: load A(k+1)->regs + B(k+1)->BNEXT; MFMA(k) from buf[k&1];
// ds_write A regs -> buf^1 (swizzled); one __syncthreads.

__global__ __launch_bounds__(512, 4) void conv_mfma_kernel(
    const short* __restrict__ y,     // [N][64] bf16
    const short* __restrict__ Wt,    // [27][128][64] bf16
    const int* __restrict__ nidx,    // [N][27]
    float* __restrict__ out) {       // [N][128] f32
  __shared__ __align__(16) short Atile[2][BM * F_IN];   // 2 x 16 KB
  __shared__ int s_idx[BM * KOFF];                      // 13.5 KB

  const int tid = threadIdx.x;
  const int wave = tid >> 6;         // 0..7
  const int lane = tid & 63;
  const int l31 = lane & 31;
  const int lhk = lane >> 5;         // 0/1: k-half of the 32x32 fragment
  const int rg = wave >> 1;          // row-group: rows rg*32..+32
  const int cg = wave & 1;           // col-group: cols cg*64..+64
  const int row0 = blockIdx.x * BM;
  const int nval = (N_VOX - row0 < BM) ? (N_VOX - row0) : BM;

  // gather geometry (r5-verbatim, independent of compute map): wave fills
  // rows [16w,16w+16); lane serves rows m0, m1=m0+8, 16B chunk c
  const int m0 = wave * 16 + (lane >> 3);
  const int m1 = m0 + 8;
  const int c = lane & 7;
  const int wr0 = m0 * 128 + ((c ^ (m0 & 7)) << 4);   // swizzled ds_write
  const int wr1 = wr0 + 1024;
  // B stream base: this lane's (col, k-half) in Wt[k][128][64]
  const short* wtb = Wt + (size_t)(cg * 64 + l31) * F_IN + lhk * 8;

  // stage this block's neighbor indices (coalesced); pad tail rows with 0
  for (int i = tid; i < BM * KOFF; i += 512)
    s_idx[i] = (i < nval * KOFF) ? nidx[(size_t)row0 * KOFF + i] : 0;
  __syncthreads();

  f32x16 acc0 = {}, acc1 = {};       // col-tiles cg*64+0..31, +32..63
  short8 BA[2][4], BB[2][4];         // B dbuf [ct][ks], static idx via unroll

  // ---- prologue: A(0) -> buf0; B(0) -> BA ----
  {
    const int g0 = s_idx[m0 * KOFF], g1 = s_idx[m1 * KOFF];
    short8 t0 = *(const short8*)(y + (size_t)g0 * F_IN + c * 8);
    short8 t1 = *(const short8*)(y + (size_t)g1 * F_IN + c * 8);
#pragma unroll
    for (int ct = 0; ct < 2; ++ct)
#pragma unroll
      for (int ks = 0; ks < 4; ++ks)
        BA[ct][ks] = *(const short8*)(wtb + ct * 2048 + ks * 16);
    *(short8*)((char*)Atile[0] + wr0) = t0;
    *(short8*)((char*)Atile[0] + wr1) = t1;
  }
  __syncthreads();

#define CONV_BODY(K, BUF, BCUR, BNEXT)                                         \
  {                                                                            \
    short8 as0, as1;                                                           \
    if ((K) + 1 < KOFF) {                                                      \
      const int g0 = s_idx[m0 * KOFF + (K) + 1];                               \
      const int g1 = s_idx[m1 * KOFF + (K) + 1];                               \
      as0 = *(const short8*)(y + (size_t)g0 * F_IN + c * 8);                   \
      as1 = *(const short8*)(y + (size_t)g1 * F_IN + c * 8);                   \
      _Pragma("unroll")                                                        \
      for (int ct = 0; ct < 2; ++ct)                                           \
        _Pragma("unroll")                                                      \
        for (int ks = 0; ks < 4; ++ks)                                         \
          (BNEXT)[ct][ks] = *(const short8*)(wtb + (size_t)((K) + 1) * 8192 +  \
                                             ct * 2048 + ks * 16);             \
    }                                                                          \
    __builtin_amdgcn_sched_barrier(0); /* loads issue before MFMA region */    \
    {                                                                          \
      const int mm = rg * 32 + l31;                                            \
      const char* abase = (const char*)Atile[BUF] + mm * 128;                  \
      const int sx = (mm & 7);                                                 \
      _Pragma("unroll")                                                        \
      for (int ks = 0; ks < 4; ++ks) {                                         \
        short8 a = *(const short8*)(abase + (((ks * 2 + lhk) ^ sx) << 4));     \
        acc0 = __builtin_amdgcn_mfma_f32_32x32x16_bf16(a, (BCUR)[0][ks],       \
                                                       acc0, 0, 0, 0);         \
        acc1 = __builtin_amdgcn_mfma_f32_32x32x16_bf16(a, (BCUR)[1][ks],       \
                                                       acc1, 0, 0, 0);         \
      }                                                                        \
    }                                                                          \
    __builtin_amdgcn_sched_barrier(0); /* keep ds_writes after MFMAs */        \
    if ((K) + 1 < KOFF) {                                                      \
      *(short8*)((char*)Atile[(BUF) ^ 1] + wr0) = as0;                         \
      *(short8*)((char*)Atile[(BUF) ^ 1] + wr1) = as1;                         \
    }                                                                          \
    __syncthreads();                                                           \
  }

  for (int k = 0; k < KOFF - 1; k += 2) {        // k = 0,2,...,24
    CONV_BODY(k, 0, BA, BB);
    CONV_BODY(k + 1, 1, BB, BA);
  }
  CONV_BODY(KOFF - 1, 0, BA, BB);                // k = 26
#undef CONV_BODY

  // ---- epilogue: 32x32 C/D layout col=lane&31, row=(r&3)+8*(r>>2)+4*lhk --
#pragma unroll
  for (int r = 0; r < 16; ++r) {
    const int row = row0 + rg * 32 + (r & 3) + 8 * (r >> 2) + 4 * lhk;
    if (row < N_VOX) {
      out[(size_t)row * F_OUT + cg * 64 + l31] = acc0[r];
      out[(size_t)row * F_OUT + cg * 64 + 32 + l31] = acc1[r];
    }
  }
}

// ---------------------------------------------------------------------------
extern "C" void kernel_launch(void* const* d_in, const int* in_sizes, int n_in,
                              void* d_out, int out_size, void* d_ws, size_t ws_size,
                              hipStream_t stream) {
  const float* x     = (const float*)d_in[0];
  const float* gamma = (const float*)d_in[1];
  const float* beta  = (const float*)d_in[2];
  const float* rmean = (const float*)d_in[3];
  const float* rvar  = (const float*)d_in[4];
  const float* W     = (const float*)d_in[5];
  const int*   nidx  = (const int*)d_in[6];
  float* out = (float*)d_out;

  // workspace layout
  short* y_bf16  = (short*)d_ws;                                      // 25.6 MB
  short* Wt_bf16 = (short*)((char*)d_ws + (size_t)N_VOX * F_IN * 2);  // 442 KB

  bn_silu_kernel<<<(N_VOX * F_IN) / (256 * 8), 256, 0, stream>>>(
      x, gamma, beta, rmean, rvar, y_bf16);

  wprep_kernel<<<(KOFF * F_OUT * 8 + 255) / 256, 256, 0, stream>>>(W, Wt_bf16);

  conv_mfma_kernel<<<(N_VOX + BM - 1) / BM, 512, 0, stream>>>(
      y_bf16, Wt_bf16, nidx, out);
}

// Round 11
// 388.817 us; speedup vs baseline: 1.1423x; 1.1423x over previous
//
#include <hip/hip_runtime.h>
#include <cstdint>
#include <cstddef>

// ---------------------------------------------------------------------------
// SparseConv3DBlock: BN(inference)+SiLU -> gather(27 neighbors) -> implicit GEMM
// N=200000, F_IN=64, F_OUT=128, K=27.  bf16 MFMA path.
//   k1: y_bf16[N][64] = silu(bn(x))
//   k2: Wt_bf16[27][128][64] = transpose(W)
//   k3: BM=128, 8 waves, 32x32x16 MFMA (32 FLOP per LDS A-byte). Wave
//       (rg4 x cg2) = 32 rows x 64 cols; per phase 4 A-ds_reads + 8 MFMA.
//       B SINGLE-buffered, loaded in-phase from L2-hot Wt (r10's B-dbuf
//       spilled: FETCH+WRITE +380MB scratch). Depth-1 reg staging, one
//       __syncthreads/phase, XOR swizzle write+read.
//   r6/r8/r10 lesson: persistent-reg demand must sit WELL under the cap.
// ---------------------------------------------------------------------------

typedef __attribute__((ext_vector_type(8))) short short8;
typedef __attribute__((ext_vector_type(16))) float f32x16;

#define N_VOX 200000
#define F_IN 64
#define F_OUT 128
#define KOFF 27
#define BM 128

__device__ __forceinline__ short f2bf(float f) {
  unsigned u = __builtin_bit_cast(unsigned, f);
  u += 0x7fffu + ((u >> 16) & 1u);   // RNE
  return (short)(u >> 16);
}

// ---------------- Kernel 1: BN + SiLU + cast to bf16 ----------------------
__global__ __launch_bounds__(256) void bn_silu_kernel(
    const float* __restrict__ x, const float* __restrict__ gamma,
    const float* __restrict__ beta, const float* __restrict__ mean,
    const float* __restrict__ var, short* __restrict__ y) {
  __shared__ float s_scale[F_IN], s_bias[F_IN];
  int tid = threadIdx.x;
  if (tid < F_IN) {
    float s = gamma[tid] * rsqrtf(var[tid] + 1e-5f);
    s_scale[tid] = s;
    s_bias[tid] = beta[tid] - mean[tid] * s;
  }
  __syncthreads();
  size_t i = ((size_t)blockIdx.x * 256 + tid) * 8;   // 12.8M total, exact
  int f0 = (int)(i & (F_IN - 1));                    // multiple of 8
  float4 x0 = *(const float4*)(x + i);
  float4 x1 = *(const float4*)(x + i + 4);
  float v[8] = {x0.x, x0.y, x0.z, x0.w, x1.x, x1.y, x1.z, x1.w};
  short8 o;
#pragma unroll
  for (int j = 0; j < 8; ++j) {
    float t = v[j] * s_scale[f0 + j] + s_bias[f0 + j];
    float sg = 1.0f / (1.0f + __expf(-t));
    o[j] = f2bf(t * sg);
  }
  *(short8*)(y + i) = o;
}

// ---------------- Kernel 2: W[27][64][128] f32 -> Wt[27][128][64] bf16 ----
__global__ __launch_bounds__(256) void wprep_kernel(
    const float* __restrict__ W, short* __restrict__ Wt) {
  int tid = blockIdx.x * 256 + threadIdx.x;        // 27*128*8 = 27648 threads
  if (tid >= KOFF * F_OUT * 8) return;
  int k = tid >> 10;                               // /(128*8)
  int r = tid & 1023;
  int o = r >> 3;
  int f0 = (r & 7) * 8;
  short8 vv;
#pragma unroll
  for (int i = 0; i < 8; ++i)
    vv[i] = f2bf(W[((size_t)k * F_IN + f0 + i) * F_OUT + o]);
  *(short8*)(Wt + ((size_t)k * F_OUT + o) * F_IN + f0) = vv;
}

// ---------------- Kernel 3: 32x32x16, B single-buffered in-phase ----------
// BM=128 voxels/block, 512 threads = 8 waves. Wave (rg=w>>1, cg=w&1):
// rows rg*32..+32, cols cg*64..+64. Per phase per wave: 8 B global loads
// (L2-hot), 2 A-gather global loads, 4 A ds_read_b128, 8 MFMA 32x32x16.
// Phase k: issue A(k+1)+B(k) loads; MFMA(k) from buf[k&1]; ds_write A(k+1)
// -> buf^1 (swizzled); one __syncthreads.

__global__ __launch_bounds__(512, 4) void conv_mfma_kernel(
    const short* __restrict__ y,     // [N][64] bf16
    const short* __restrict__ Wt,    // [27][128][64] bf16
    const int* __restrict__ nidx,    // [N][27]
    float* __restrict__ out) {       // [N][128] f32
  __shared__ __align__(16) short Atile[2][BM * F_IN];   // 2 x 16 KB
  __shared__ int s_idx[BM * KOFF];                      // 13.5 KB

  const int tid = threadIdx.x;
  const int wave = tid >> 6;         // 0..7
  const int lane = tid & 63;
  const int l31 = lane & 31;
  const int lhk = lane >> 5;         // 0/1: k-half of the 32x32 fragment
  const int rg = wave >> 1;          // row-group: rows rg*32..+32
  const int cg = wave & 1;           // col-group: cols cg*64..+64
  const int row0 = blockIdx.x * BM;
  const int nval = (N_VOX - row0 < BM) ? (N_VOX - row0) : BM;

  // gather geometry (r5-verbatim): wave fills rows [16w,16w+16);
  // lane serves rows m0, m1=m0+8, 16B chunk c
  const int m0 = wave * 16 + (lane >> 3);
  const int m1 = m0 + 8;
  const int c = lane & 7;
  const int wr0 = m0 * 128 + ((c ^ (m0 & 7)) << 4);   // swizzled ds_write
  const int wr1 = wr0 + 1024;
  // B stream base: this lane's (col, k-half) in Wt[k][128][64]
  const short* wtb = Wt + (size_t)(cg * 64 + l31) * F_IN + lhk * 8;

  // stage this block's neighbor indices (coalesced); pad tail rows with 0
  for (int i = tid; i < BM * KOFF; i += 512)
    s_idx[i] = (i < nval * KOFF) ? nidx[(size_t)row0 * KOFF + i] : 0;
  __syncthreads();

  f32x16 acc0 = {}, acc1 = {};       // col-tiles cg*64+0..31, +32..63

  // ---- prologue: A(0) -> buf0 ----
  {
    const int g0 = s_idx[m0 * KOFF], g1 = s_idx[m1 * KOFF];
    short8 t0 = *(const short8*)(y + (size_t)g0 * F_IN + c * 8);
    short8 t1 = *(const short8*)(y + (size_t)g1 * F_IN + c * 8);
    *(short8*)((char*)Atile[0] + wr0) = t0;
    *(short8*)((char*)Atile[0] + wr1) = t1;
  }
  __syncthreads();

#define CONV_BODY(K, BUF)                                                      \
  {                                                                            \
    short8 as0, as1;                                                           \
    if ((K) + 1 < KOFF) {                                                      \
      const int g0 = s_idx[m0 * KOFF + (K) + 1];                               \
      const int g1 = s_idx[m1 * KOFF + (K) + 1];                               \
      as0 = *(const short8*)(y + (size_t)g0 * F_IN + c * 8);                   \
      as1 = *(const short8*)(y + (size_t)g1 * F_IN + c * 8);                   \
    }                                                                          \
    /* B(K): single-buffered, L2-hot (issued before MFMA region) */            \
    short8 bq[2][4];                                                           \
    _Pragma("unroll")                                                          \
    for (int ct = 0; ct < 2; ++ct)                                             \
      _Pragma("unroll")                                                        \
      for (int ks = 0; ks < 4; ++ks)                                           \
        bq[ct][ks] = *(const short8*)(wtb + (size_t)(K) * 8192 +               \
                                      ct * 2048 + ks * 16);                    \
    __builtin_amdgcn_sched_barrier(0); /* loads issue before MFMA region */    \
    {                                                                          \
      const int mm = rg * 32 + l31;                                            \
      const char* abase = (const char*)Atile[BUF] + mm * 128;                  \
      const int sx = (mm & 7);                                                 \
      _Pragma("unroll")                                                        \
      for (int ks = 0; ks < 4; ++ks) {                                         \
        short8 a = *(const short8*)(abase + (((ks * 2 + lhk) ^ sx) << 4));     \
        acc0 = __builtin_amdgcn_mfma_f32_32x32x16_bf16(a, bq[0][ks],           \
                                                       acc0, 0, 0, 0);         \
        acc1 = __builtin_amdgcn_mfma_f32_32x32x16_bf16(a, bq[1][ks],           \
                                                       acc1, 0, 0, 0);         \
      }                                                                        \
    }                                                                          \
    __builtin_amdgcn_sched_barrier(0); /* keep ds_writes after MFMAs */        \
    if ((K) + 1 < KOFF) {                                                      \
      *(short8*)((char*)Atile[(BUF) ^ 1] + wr0) = as0;                         \
      *(short8*)((char*)Atile[(BUF) ^ 1] + wr1) = as1;                         \
    }                                                                          \
    __syncthreads();                                                           \
  }

  for (int k = 0; k < KOFF - 1; k += 2) {        // k = 0,2,...,24
    CONV_BODY(k, 0);
    CONV_BODY(k + 1, 1);
  }
  CONV_BODY(KOFF - 1, 0);                        // k = 26
#undef CONV_BODY

  // ---- epilogue: 32x32 C/D layout col=lane&31, row=(r&3)+8*(r>>2)+4*lhk --
#pragma unroll
  for (int r = 0; r < 16; ++r) {
    const int row = row0 + rg * 32 + (r & 3) + 8 * (r >> 2) + 4 * lhk;
    if (row < N_VOX) {
      out[(size_t)row * F_OUT + cg * 64 + l31] = acc0[r];
      out[(size_t)row * F_OUT + cg * 64 + 32 + l31] = acc1[r];
    }
  }
}

// ---------------------------------------------------------------------------
extern "C" void kernel_launch(void* const* d_in, const int* in_sizes, int n_in,
                              void* d_out, int out_size, void* d_ws, size_t ws_size,
                              hipStream_t stream) {
  const float* x     = (const float*)d_in[0];
  const float* gamma = (const float*)d_in[1];
  const float* beta  = (const float*)d_in[2];
  const float* rmean = (const float*)d_in[3];
  const float* rvar  = (const float*)d_in[4];
  const float* W     = (const float*)d_in[5];
  const int*   nidx  = (const int*)d_in[6];
  float* out = (float*)d_out;

  // workspace layout
  short* y_bf16  = (short*)d_ws;                                      // 25.6 MB
  short* Wt_bf16 = (short*)((char*)d_ws + (size_t)N_VOX * F_IN * 2);  // 442 KB

  bn_silu_kernel<<<(N_VOX * F_IN) / (256 * 8), 256, 0, stream>>>(
      x, gamma, beta, rmean, rvar, y_bf16);

  wprep_kernel<<<(KOFF * F_OUT * 8 + 255) / 256, 256, 0, stream>>>(W, Wt_bf16);

  conv_mfma_kernel<<<(N_VOX + BM - 1) / BM, 512, 0, stream>>>(
      y_bf16, Wt_bf16, nidx, out);
}

// Round 12
// 217.155 us; speedup vs baseline: 2.0454x; 1.7905x over previous
//
#include <hip/hip_runtime.h>
#include <cstdint>
#include <cstddef>

// ---------------------------------------------------------------------------
// SparseConv3DBlock: BN(inference)+SiLU -> gather(27 neighbors) -> implicit GEMM
// N=200000, F_IN=64, F_OUT=128, K=27.  bf16 MFMA path.
//   k1: y_bf16[N][64] = silu(bn(x))
//   k2: Wt_bf16[27][128][64] = transpose(W)
//   k3: r5 skeleton (BM=128, 8 waves, wave=128rows x 16cols, 16x16x32,
//       reg-staged gather, XOR swizzle) but TWO k-offsets per super-phase
//       with FOUR LDS buffers: super(k) reads bufs {k%4,(k+1)%4}, writes
//       {(k+2)%4,(k+3)%4} (disjoint -> ONE __syncthreads per super-phase).
//       32 MFMA per barrier (was 16), 14 barriers (was 27). No s_idx LDS.
//   Lessons: r4 no hand vmcnt; r6/r8/r10 keep VGPR under cap; r9/r11 don't
//   restructure tiles/B-buffering away from r5.
// ---------------------------------------------------------------------------

typedef __attribute__((ext_vector_type(8))) short short8;
typedef __attribute__((ext_vector_type(4))) float f32x4;

#define N_VOX 200000
#define F_IN 64
#define F_OUT 128
#define KOFF 27
#define BM 128

__device__ __forceinline__ short f2bf(float f) {
  unsigned u = __builtin_bit_cast(unsigned, f);
  u += 0x7fffu + ((u >> 16) & 1u);   // RNE
  return (short)(u >> 16);
}

// ---------------- Kernel 1: BN + SiLU + cast to bf16 ----------------------
__global__ __launch_bounds__(256) void bn_silu_kernel(
    const float* __restrict__ x, const float* __restrict__ gamma,
    const float* __restrict__ beta, const float* __restrict__ mean,
    const float* __restrict__ var, short* __restrict__ y) {
  __shared__ float s_scale[F_IN], s_bias[F_IN];
  int tid = threadIdx.x;
  if (tid < F_IN) {
    float s = gamma[tid] * rsqrtf(var[tid] + 1e-5f);
    s_scale[tid] = s;
    s_bias[tid] = beta[tid] - mean[tid] * s;
  }
  __syncthreads();
  size_t i = ((size_t)blockIdx.x * 256 + tid) * 8;   // 12.8M total, exact
  int f0 = (int)(i & (F_IN - 1));                    // multiple of 8
  float4 x0 = *(const float4*)(x + i);
  float4 x1 = *(const float4*)(x + i + 4);
  float v[8] = {x0.x, x0.y, x0.z, x0.w, x1.x, x1.y, x1.z, x1.w};
  short8 o;
#pragma unroll
  for (int j = 0; j < 8; ++j) {
    float t = v[j] * s_scale[f0 + j] + s_bias[f0 + j];
    float sg = 1.0f / (1.0f + __expf(-t));
    o[j] = f2bf(t * sg);
  }
  *(short8*)(y + i) = o;
}

// ---------------- Kernel 2: W[27][64][128] f32 -> Wt[27][128][64] bf16 ----
__global__ __launch_bounds__(256) void wprep_kernel(
    const float* __restrict__ W, short* __restrict__ Wt) {
  int tid = blockIdx.x * 256 + threadIdx.x;        // 27*128*8 = 27648 threads
  if (tid >= KOFF * F_OUT * 8) return;
  int k = tid >> 10;                               // /(128*8)
  int r = tid & 1023;
  int o = r >> 3;
  int f0 = (r & 7) * 8;
  short8 vv;
#pragma unroll
  for (int i = 0; i < 8; ++i)
    vv[i] = f2bf(W[((size_t)k * F_IN + f0 + i) * F_OUT + o]);
  *(short8*)(Wt + ((size_t)k * F_OUT + o) * F_IN + f0) = vv;
}

// ---------------- Kernel 3: 2k-superphase reg-staged gather + GEMM --------
// BM=128 voxels/block, 512 threads = 8 waves. Wave w: rows 0..127 x cols
// [16w,16w+16): 8 row-tiles, 32 MFMA per super-phase (2 k-offsets).
// Super(k): gather A(k+2),A(k+3)->regs; B(k+2),B(k+3)->BQ; idx(k+4..5);
// MFMA(k) from buf[k%4], MFMA(k+1) from buf[(k+1)%4]; ds_write A regs ->
// buf[(k+2)%4], buf[(k+3)%4]; ONE __syncthreads.

__global__ __launch_bounds__(512, 4) void conv_mfma_kernel(
    const short* __restrict__ y,     // [N][64] bf16
    const short* __restrict__ Wt,    // [27][128][64] bf16
    const int* __restrict__ nidx,    // [N][27]
    float* __restrict__ out) {       // [N][128] f32
  __shared__ __align__(16) short Atile[4][BM * F_IN];   // 4 x 16 KB = 64 KB

  const int tid = threadIdx.x;
  const int wave = tid >> 6;         // 0..7
  const int lane = tid & 63;
  const int lhi = lane >> 4;         // 0..3
  const int llo = lane & 15;
  const int row0 = blockIdx.x * BM;

  // gather geometry (r5-verbatim): lane serves rows m0, m1=m0+8, chunk c
  const int m0 = wave * 16 + (lane >> 3);
  const int m1 = m0 + 8;
  const int c = lane & 7;
  const int wr0 = m0 * 128 + ((c ^ (m0 & 7)) << 4);   // swizzled ds_write
  const int wr1 = wr0 + 1024;
  // per-lane idx streams (8 lanes share each address -> HW broadcast;
  // clamp tail rows; stores masked in epilogue)
  const int gr0 = (row0 + m0 < N_VOX) ? row0 + m0 : N_VOX - 1;
  const int gr1 = (row0 + m1 < N_VOX) ? row0 + m1 : N_VOX - 1;
  const int* ip0 = nidx + (size_t)gr0 * KOFF;
  const int* ip1 = nidx + (size_t)gr1 * KOFF;
  // B stream: wave's col slice, per-lane frag base (r5-verbatim)
  const short* wtp = Wt + (size_t)(wave * 16 + llo) * F_IN + lhi * 8;

  f32x4 acc[8] = {};
  short8 BPa[2][2], BPb[2][2];       // B sets: [kk within pair][kt k-half]
  int ia0, ia1, ib0, ib1;            // idx sets (rows m0,m1), alternate
  int ja0, ja1, jb0, jb1;

  // ---- prologue: A(0)->buf0, A(1)->buf1; B(0),B(1)->BPa; idx(2),(3) ----
  {
    const int g0 = ip0[0], g1 = ip1[0], h0 = ip0[1], h1 = ip1[1];
    short8 t0 = *(const short8*)(y + (size_t)g0 * F_IN + c * 8);
    short8 t1 = *(const short8*)(y + (size_t)g1 * F_IN + c * 8);
    short8 t2 = *(const short8*)(y + (size_t)h0 * F_IN + c * 8);
    short8 t3 = *(const short8*)(y + (size_t)h1 * F_IN + c * 8);
    ia0 = ip0[2]; ia1 = ip1[2]; ja0 = ip0[3]; ja1 = ip1[3];
#pragma unroll
    for (int kt = 0; kt < 2; ++kt) {
      BPa[0][kt] = *(const short8*)(wtp + kt * 32);
      BPa[1][kt] = *(const short8*)(wtp + 8192 + kt * 32);
    }
    *(short8*)((char*)Atile[0] + wr0) = t0;
    *(short8*)((char*)Atile[0] + wr1) = t1;
    *(short8*)((char*)Atile[1] + wr0) = t2;
    *(short8*)((char*)Atile[1] + wr1) = t3;
  }
  __syncthreads();

  // MFMA half-phase: 16 MFMA from buffer RB with B pair BP[kk]
#define MFMA_HALF(RB, BPK)                                                     \
  _Pragma("unroll")                                                            \
  for (int rt = 0; rt < 8; ++rt) {                                             \
    const int mm = rt * 16 + llo;                                              \
    const int base = mm * 128 + lhi * 16;                                      \
    const int swz = (mm & 7) << 4;                                             \
    short8 a0 = *(const short8*)((const char*)Atile[RB] + (base ^ swz));       \
    short8 a1 = *(const short8*)((const char*)Atile[RB] + ((base + 64) ^ swz));\
    acc[rt] = __builtin_amdgcn_mfma_f32_16x16x32_bf16(a0, (BPK)[0],            \
                                                      acc[rt], 0, 0, 0);       \
    acc[rt] = __builtin_amdgcn_mfma_f32_16x16x32_bf16(a1, (BPK)[1],            \
                                                      acc[rt], 0, 0, 0);       \
  }

  // SUPER(K): reads bufs R0,R1; writes W0,W1 (disjoint). BP consumed,
  // BQ loaded with B(K+2),B(K+3). IC* consumed (gathers A(K+2),A(K+3)),
  // IN* loaded with idx(K+4),(K+5).
#define SUPER(K, R0, R1, W0, W1, BP, BQ, IC2_0, IC2_1, IC3_0, IC3_1,           \
              IN4_0, IN4_1, IN5_0, IN5_1)                                      \
  {                                                                            \
    short8 as0, as1, as2, as3;                                                 \
    if ((K) + 2 < KOFF) {                                                      \
      as0 = *(const short8*)(y + (size_t)IC2_0 * F_IN + c * 8);                \
      as1 = *(const short8*)(y + (size_t)IC2_1 * F_IN + c * 8);                \
      _Pragma("unroll")                                                        \
      for (int kt = 0; kt < 2; ++kt)                                           \
        (BQ)[0][kt] =                                                          \
            *(const short8*)(wtp + (size_t)((K) + 2) * 8192 + kt * 32);        \
    }                                                                          \
    if ((K) + 3 < KOFF) {                                                      \
      as2 = *(const short8*)(y + (size_t)IC3_0 * F_IN + c * 8);                \
      as3 = *(const short8*)(y + (size_t)IC3_1 * F_IN + c * 8);                \
      _Pragma("unroll")                                                        \
      for (int kt = 0; kt < 2; ++kt)                                           \
        (BQ)[1][kt] =                                                          \
            *(const short8*)(wtp + (size_t)((K) + 3) * 8192 + kt * 32);        \
    }                                                                          \
    if ((K) + 4 < KOFF) { IN4_0 = ip0[(K) + 4]; IN4_1 = ip1[(K) + 4]; }        \
    if ((K) + 5 < KOFF) { IN5_0 = ip0[(K) + 5]; IN5_1 = ip1[(K) + 5]; }        \
    __builtin_amdgcn_sched_barrier(0); /* loads issued before MFMA region */   \
    __builtin_amdgcn_s_setprio(1);                                             \
    MFMA_HALF(R0, (BP)[0])                                                     \
    MFMA_HALF(R1, (BP)[1])                                                     \
    __builtin_amdgcn_s_setprio(0);                                             \
    __builtin_amdgcn_sched_barrier(0); /* ds_writes stay after MFMAs */        \
    if ((K) + 2 < KOFF) {                                                      \
      *(short8*)((char*)Atile[W0] + wr0) = as0;                                \
      *(short8*)((char*)Atile[W0] + wr1) = as1;                                \
    }                                                                          \
    if ((K) + 3 < KOFF) {                                                      \
      *(short8*)((char*)Atile[W1] + wr0) = as2;                                \
      *(short8*)((char*)Atile[W1] + wr1) = as3;                                \
    }                                                                          \
    __syncthreads();                                                           \
  }

  // supers K=0,2,...,22 (pairs), then K=24, then final k=26 half-phase
  for (int k = 0; k < 24; k += 4) {
    SUPER(k, 0, 1, 2, 3, BPa, BPb, ia0, ia1, ja0, ja1, ib0, ib1, jb0, jb1);
    SUPER(k + 2, 2, 3, 0, 1, BPb, BPa, ib0, ib1, jb0, jb1, ia0, ia1, ja0, ja1);
  }
  SUPER(24, 0, 1, 2, 3, BPa, BPb, ia0, ia1, ja0, ja1, ib0, ib1, jb0, jb1);
  // k=26: read buf2, B(26) is in BPb[0]
  __builtin_amdgcn_s_setprio(1);
  MFMA_HALF(2, BPb[0])
  __builtin_amdgcn_s_setprio(0);
#undef SUPER
#undef MFMA_HALF

  // ---- epilogue: C/D layout col=lane&15, row=(lane>>4)*4+j ----
#pragma unroll
  for (int rt = 0; rt < 8; ++rt) {
    const int col = wave * 16 + llo;
    const int rbase = row0 + rt * 16 + lhi * 4;
#pragma unroll
    for (int j = 0; j < 4; ++j) {
      const int row = rbase + j;
      if (row < N_VOX) out[(size_t)row * F_OUT + col] = acc[rt][j];
    }
  }
}

// ---------------------------------------------------------------------------
extern "C" void kernel_launch(void* const* d_in, const int* in_sizes, int n_in,
                              void* d_out, int out_size, void* d_ws, size_t ws_size,
                              hipStream_t stream) {
  const float* x     = (const float*)d_in[0];
  const float* gamma = (const float*)d_in[1];
  const float* beta  = (const float*)d_in[2];
  const float* rmean = (const float*)d_in[3];
  const float* rvar  = (const float*)d_in[4];
  const float* W     = (const float*)d_in[5];
  const int*   nidx  = (const int*)d_in[6];
  float* out = (float*)d_out;

  // workspace layout
  short* y_bf16  = (short*)d_ws;                                      // 25.6 MB
  short* Wt_bf16 = (short*)((char*)d_ws + (size_t)N_VOX * F_IN * 2);  // 442 KB

  bn_silu_kernel<<<(N_VOX * F_IN) / (256 * 8), 256, 0, stream>>>(
      x, gamma, beta, rmean, rvar, y_bf16);

  wprep_kernel<<<(KOFF * F_OUT * 8 + 255) / 256, 256, 0, stream>>>(W, Wt_bf16);

  conv_mfma_kernel<<<(N_VOX + BM - 1) / BM, 512, 0, stream>>>(
      y_bf16, Wt_bf16, nidx, out);
}

// Round 13
// 180.776 us; speedup vs baseline: 2.4570x; 1.2012x over previous
//
#include <hip/hip_runtime.h>
#include <cstdint>
#include <cstddef>

// ---------------------------------------------------------------------------
// SparseConv3DBlock: BN(inference)+SiLU -> gather(27 neighbors) -> implicit GEMM
// N=200000, F_IN=64, F_OUT=128, K=27.  bf16 MFMA path.
//   k1: y_bf16[N][64] = silu(bn(x))
//   k2: Wt_bf16[27][128][64] = transpose(W)
//   k3: r5/r7 skeleton (BM=128, 8 waves, wave=128rows x 16cols, 16x16x32,
//       reg-staged gather, XOR swizzle, 2 LDS buffers, 1 barrier/phase) but
//       DEPTH-3 staging + NON-DRAINING barrier: __syncthreads drains
//       vmcnt(0) (killed all prefetch depth, r2..r12); replaced with
//       {sched_barrier; s_waitcnt lgkmcnt(0); s_barrier; sched_barrier}
//       so register-gathers stay in flight across phases. All vmcnt waits
//       stay compiler-tracked register dependences (r4 lesson: no hand counts).
// ---------------------------------------------------------------------------

typedef __attribute__((ext_vector_type(8))) short short8;
typedef __attribute__((ext_vector_type(4))) float f32x4;

#define N_VOX 200000
#define F_IN 64
#define F_OUT 128
#define KOFF 27
#define BM 128

__device__ __forceinline__ short f2bf(float f) {
  unsigned u = __builtin_bit_cast(unsigned, f);
  u += 0x7fffu + ((u >> 16) & 1u);   // RNE
  return (short)(u >> 16);
}

// ---------------- Kernel 1: BN + SiLU + cast to bf16 ----------------------
__global__ __launch_bounds__(256) void bn_silu_kernel(
    const float* __restrict__ x, const float* __restrict__ gamma,
    const float* __restrict__ beta, const float* __restrict__ mean,
    const float* __restrict__ var, short* __restrict__ y) {
  __shared__ float s_scale[F_IN], s_bias[F_IN];
  int tid = threadIdx.x;
  if (tid < F_IN) {
    float s = gamma[tid] * rsqrtf(var[tid] + 1e-5f);
    s_scale[tid] = s;
    s_bias[tid] = beta[tid] - mean[tid] * s;
  }
  __syncthreads();
  size_t i = ((size_t)blockIdx.x * 256 + tid) * 8;   // 12.8M total, exact
  int f0 = (int)(i & (F_IN - 1));                    // multiple of 8
  float4 x0 = *(const float4*)(x + i);
  float4 x1 = *(const float4*)(x + i + 4);
  float v[8] = {x0.x, x0.y, x0.z, x0.w, x1.x, x1.y, x1.z, x1.w};
  short8 o;
#pragma unroll
  for (int j = 0; j < 8; ++j) {
    float t = v[j] * s_scale[f0 + j] + s_bias[f0 + j];
    float sg = 1.0f / (1.0f + __expf(-t));
    o[j] = f2bf(t * sg);
  }
  *(short8*)(y + i) = o;
}

// ---------------- Kernel 2: W[27][64][128] f32 -> Wt[27][128][64] bf16 ----
__global__ __launch_bounds__(256) void wprep_kernel(
    const float* __restrict__ W, short* __restrict__ Wt) {
  int tid = blockIdx.x * 256 + threadIdx.x;        // 27*128*8 = 27648 threads
  if (tid >= KOFF * F_OUT * 8) return;
  int k = tid >> 10;                               // /(128*8)
  int r = tid & 1023;
  int o = r >> 3;
  int f0 = (r & 7) * 8;
  short8 vv;
#pragma unroll
  for (int i = 0; i < 8; ++i)
    vv[i] = f2bf(W[((size_t)k * F_IN + f0 + i) * F_OUT + o]);
  *(short8*)(Wt + ((size_t)k * F_OUT + o) * F_IN + f0) = vv;
}

// ---------------- Kernel 3: depth-3 staged gather, non-draining barrier ---
// BM=128, 512 threads = 8 waves. Wave w: rows 0..127 x cols [16w,16w+16).
// Phase K: issue gather A(K+3)->set(K%3); load idx(K+4), B(K+1);
// ds_write A(K+1) (set (K+1)%3, in flight 2 phases) -> buf[(K+1)&1];
// MFMA(K) from buf[K&1]; lgkmcnt(0)-only barrier (gathers stay in flight).

__global__ __launch_bounds__(512, 4) void conv_mfma_kernel(
    const short* __restrict__ y,     // [N][64] bf16
    const short* __restrict__ Wt,    // [27][128][64] bf16
    const int* __restrict__ nidx,    // [N][27]
    float* __restrict__ out) {       // [N][128] f32
  __shared__ __align__(16) short Atile[2][BM * F_IN];   // 2 x 16 KB

  const int tid = threadIdx.x;
  const int wave = tid >> 6;         // 0..7
  const int lane = tid & 63;
  const int lhi = lane >> 4;         // 0..3
  const int llo = lane & 15;
  const int row0 = blockIdx.x * BM;

  // gather geometry (r5-verbatim): lane serves rows m0, m1=m0+8, chunk c
  const int m0 = wave * 16 + (lane >> 3);
  const int m1 = m0 + 8;
  const int c = lane & 7;
  const int wr0 = m0 * 128 + ((c ^ (m0 & 7)) << 4);   // swizzled ds_write
  const int wr1 = wr0 + 1024;
  // per-lane idx streams (8 lanes share addr -> broadcast; clamp tail rows)
  const int gr0 = (row0 + m0 < N_VOX) ? row0 + m0 : N_VOX - 1;
  const int gr1 = (row0 + m1 < N_VOX) ? row0 + m1 : N_VOX - 1;
  const int* ip0 = nidx + (size_t)gr0 * KOFF;
  const int* ip1 = nidx + (size_t)gr1 * KOFF;
  // B stream: wave's col slice, per-lane frag base
  const short* wtp = Wt + (size_t)(wave * 16 + llo) * F_IN + lhi * 8;

  f32x4 acc[8] = {};
  short8 s0a, s0b, s1a, s1b, s2a, s2b;   // A staging sets (rotate mod 3)
  short8 BA[2], BB[2];                   // B sets (alternate)
  int iA0, iA1, iB0, iB1;                // idx sets (alternate)

  // ---- prologue: issue A(0),A(1),A(2); iA=idx(3); B(0)->BA;
  //      ds_write A(0)->buf0; non-draining barrier (A(1),A(2) in flight) ----
  {
    const int g0 = ip0[0], g1 = ip1[0];
    const int h0 = ip0[1], h1 = ip1[1];
    const int e0 = ip0[2], e1 = ip1[2];
    s0a = *(const short8*)(y + (size_t)g0 * F_IN + c * 8);
    s0b = *(const short8*)(y + (size_t)g1 * F_IN + c * 8);
    s1a = *(const short8*)(y + (size_t)h0 * F_IN + c * 8);
    s1b = *(const short8*)(y + (size_t)h1 * F_IN + c * 8);
    s2a = *(const short8*)(y + (size_t)e0 * F_IN + c * 8);
    s2b = *(const short8*)(y + (size_t)e1 * F_IN + c * 8);
    iA0 = ip0[3]; iA1 = ip1[3];
    BA[0] = *(const short8*)(wtp);
    BA[1] = *(const short8*)(wtp + 32);
    *(short8*)((char*)Atile[0] + wr0) = s0a;   // vmcnt wait: s0 only
    *(short8*)((char*)Atile[0] + wr1) = s0b;
  }
  __builtin_amdgcn_sched_barrier(0);
  asm volatile("s_waitcnt lgkmcnt(0)" ::: "memory");
  __builtin_amdgcn_s_barrier();
  __builtin_amdgcn_sched_barrier(0);

  // PHASE(K): RBUF=K&1. SI*=set K%3 (receives A(K+3)); SW*=set (K+1)%3
  // (holds A(K+1), written to buf RBUF^1). BCUR=B(K); BNEXT gets B(K+1).
  // IU*=idx(K+3) (set K&1, consumed); IL*=set ~K&1 (gets idx(K+4)).
#define PHASE(K, RBUF, SIa, SIb, SWa, SWb, BCUR, BNEXT, IUa, IUb, ILa, ILb)    \
  {                                                                            \
    if ((K) + 3 < KOFF) {                                                      \
      SIa = *(const short8*)(y + (size_t)(IUa) * F_IN + c * 8);                \
      SIb = *(const short8*)(y + (size_t)(IUb) * F_IN + c * 8);                \
    }                                                                          \
    if ((K) + 4 < KOFF) {                                                      \
      ILa = ip0[(K) + 4];                                                      \
      ILb = ip1[(K) + 4];                                                      \
    }                                                                          \
    if ((K) + 1 < KOFF) {                                                      \
      (BNEXT)[0] = *(const short8*)(wtp + (size_t)((K) + 1) * 8192);           \
      (BNEXT)[1] = *(const short8*)(wtp + (size_t)((K) + 1) * 8192 + 32);      \
      *(short8*)((char*)Atile[(RBUF) ^ 1] + wr0) = SWa;                        \
      *(short8*)((char*)Atile[(RBUF) ^ 1] + wr1) = SWb;                        \
    }                                                                          \
    __builtin_amdgcn_sched_barrier(0);                                         \
    _Pragma("unroll")                                                          \
    for (int rt = 0; rt < 8; ++rt) {                                           \
      const int mm = rt * 16 + llo;                                            \
      const int base = mm * 128 + lhi * 16;                                    \
      const int swz = (mm & 7) << 4;                                           \
      short8 a0 = *(const short8*)((const char*)Atile[RBUF] + (base ^ swz));   \
      short8 a1 =                                                              \
          *(const short8*)((const char*)Atile[RBUF] + ((base + 64) ^ swz));    \
      acc[rt] = __builtin_amdgcn_mfma_f32_16x16x32_bf16(a0, (BCUR)[0],         \
                                                        acc[rt], 0, 0, 0);     \
      acc[rt] = __builtin_amdgcn_mfma_f32_16x16x32_bf16(a1, (BCUR)[1],         \
                                                        acc[rt], 0, 0, 0);     \
    }                                                                          \
    __builtin_amdgcn_sched_barrier(0);                                         \
    if ((K) + 1 < KOFF) {                                                      \
      asm volatile("s_waitcnt lgkmcnt(0)" ::: "memory");                       \
      __builtin_amdgcn_s_barrier();                                            \
      __builtin_amdgcn_sched_barrier(0);                                       \
    }                                                                          \
  }

  // period-6 schedule: k%6 -> (RBUF, SI, SW, BCUR/BNEXT, IU/IL)
  for (int k = 0; k < 24; k += 6) {
    PHASE(k + 0, 0, s0a, s0b, s1a, s1b, BA, BB, iA0, iA1, iB0, iB1);
    PHASE(k + 1, 1, s1a, s1b, s2a, s2b, BB, BA, iB0, iB1, iA0, iA1);
    PHASE(k + 2, 0, s2a, s2b, s0a, s0b, BA, BB, iA0, iA1, iB0, iB1);
    PHASE(k + 3, 1, s0a, s0b, s1a, s1b, BB, BA, iB0, iB1, iA0, iA1);
    PHASE(k + 4, 0, s1a, s1b, s2a, s2b, BA, BB, iA0, iA1, iB0, iB1);
    PHASE(k + 5, 1, s2a, s2b, s0a, s0b, BB, BA, iB0, iB1, iA0, iA1);
  }
  PHASE(24, 0, s0a, s0b, s1a, s1b, BA, BB, iA0, iA1, iB0, iB1);
  PHASE(25, 1, s1a, s1b, s2a, s2b, BB, BA, iB0, iB1, iA0, iA1);
  PHASE(26, 0, s2a, s2b, s0a, s0b, BA, BB, iA0, iA1, iB0, iB1);
#undef PHASE

  // ---- epilogue: C/D layout col=lane&15, row=(lane>>4)*4+j ----
#pragma unroll
  for (int rt = 0; rt < 8; ++rt) {
    const int col = wave * 16 + llo;
    const int rbase = row0 + rt * 16 + lhi * 4;
#pragma unroll
    for (int j = 0; j < 4; ++j) {
      const int row = rbase + j;
      if (row < N_VOX) out[(size_t)row * F_OUT + col] = acc[rt][j];
    }
  }
}

// ---------------------------------------------------------------------------
extern "C" void kernel_launch(void* const* d_in, const int* in_sizes, int n_in,
                              void* d_out, int out_size, void* d_ws, size_t ws_size,
                              hipStream_t stream) {
  const float* x     = (const float*)d_in[0];
  const float* gamma = (const float*)d_in[1];
  const float* beta  = (const float*)d_in[2];
  const float* rmean = (const float*)d_in[3];
  const float* rvar  = (const float*)d_in[4];
  const float* W     = (const float*)d_in[5];
  const int*   nidx  = (const int*)d_in[6];
  float* out = (float*)d_out;

  // workspace layout
  short* y_bf16  = (short*)d_ws;                                      // 25.6 MB
  short* Wt_bf16 = (short*)((char*)d_ws + (size_t)N_VOX * F_IN * 2);  // 442 KB

  bn_silu_kernel<<<(N_VOX * F_IN) / (256 * 8), 256, 0, stream>>>(
      x, gamma, beta, rmean, rvar, y_bf16);

  wprep_kernel<<<(KOFF * F_OUT * 8 + 255) / 256, 256, 0, stream>>>(W, Wt_bf16);

  conv_mfma_kernel<<<(N_VOX + BM - 1) / BM, 512, 0, stream>>>(
      y_bf16, Wt_bf16, nidx, out);
}